// Round 5
// baseline (312.327 us; speedup 1.0000x reference)
//
#include <hip/hip_runtime.h>

#define N 8192
#define NBLK 512
#define CAP 64
#define THR 0.2f

// ---- workspace layout (bytes) ----
// 0       bar counter (memset 256B each replay)
// 256     cnt      u32[8192]   32KB
// 33024   premask  u64[8192]   64KB
// 98560   order    u32[8192]   32KB
// 131328  sboxes   f4 [8192]  128KB
// 262400  edgesT   u64[16384] 128KB  (= edgesTS u16[65536])
// 393472  edgesOvf u16[8192*56] 896KB

__device__ __forceinline__ bool iou_over(const float4 A, const float4 B) {
    float areaA = __fmul_rn(__fsub_rn(A.z, A.x), __fsub_rn(A.w, A.y));
    float areaB = __fmul_rn(__fsub_rn(B.z, B.x), __fsub_rn(B.w, B.y));
    float ix1 = fmaxf(A.x, B.x);
    float iy1 = fmaxf(A.y, B.y);
    float ix2 = fminf(A.z, B.z);
    float iy2 = fminf(A.w, B.w);
    float iw = fmaxf(__fsub_rn(ix2, ix1), 0.0f);
    float ih = fmaxf(__fsub_rn(iy2, iy1), 0.0f);
    float inter = __fmul_rn(iw, ih);
    float uni = __fsub_rn(__fadd_rn(areaA, areaB), inter);
    float iou = __fdiv_rn(inter, fmaxf(uni, 1e-9f));
    return iou > THR;
}

// ---- grid barrier helpers (monotonic counter; zeroed by memset node per replay) ----
__device__ __forceinline__ void bar_arrive(unsigned* bar) {
    __threadfence();
    __syncthreads();
    if (threadIdx.x == 0)
        __hip_atomic_fetch_add(bar, 1u, __ATOMIC_RELEASE, __HIP_MEMORY_SCOPE_AGENT);
}
__device__ __forceinline__ void bar_wait(unsigned* bar, unsigned target) {
    if (threadIdx.x == 0) {
        while (__hip_atomic_load(bar, __ATOMIC_ACQUIRE, __HIP_MEMORY_SCOPE_AGENT) < target)
            __builtin_amdgcn_s_sleep(8);
    }
    __syncthreads();
    (void)__hip_atomic_load(bar, __ATOMIC_ACQUIRE, __HIP_MEMORY_SCOPE_AGENT);
}

// ---- resolve-wave macros (R4-proven logic; keptw -> LDS) ----
#define PF(B, CH) do { \
    int ch_ = (CH); \
    if (ch_ < 128) { \
        int pb_ = ch_ * 64 + lane; \
        pm##B = prem[pb_]; \
        n##B  = cnt[pb_]; \
        ea##B = edgesT[(ch_ * 2 + 0) * 64 + lane]; \
        eb##B = edgesT[(ch_ * 2 + 1) * 64 + lane]; \
    } \
} while (0)

#define APPLY(i, W, SH) { \
    unsigned d_ = (unsigned)((W) >> (SH)) & 0xFFFFu; \
    bool v_ = (i) < nn_; \
    unsigned a_ = v_ ? (d_ >> 5) : (unsigned)lane; \
    unsigned m_ = v_ ? ~(1u << (d_ & 31)) : ~0u; \
    atomicAnd(&alive[a_], m_); }

#define STEP(B, C) do { \
    const unsigned av_ = (alive[(C) * 2 + (lane >> 5)] >> (lane & 31)) & 1u; \
    unsigned long long anz = __ballot(pm##B != 0ull); \
    unsigned long long kept = __ballot(av_ != 0u); \
    if (anz != 0ull) { \
        bool mydec = !av_ || (pm##B == 0ull); \
        unsigned long long decided = __ballot(mydec); \
        kept = __ballot(av_ && (pm##B == 0ull)); \
        while (decided != ~0ull) { \
            bool ready = !mydec && ((pm##B & ~decided) == 0ull); \
            bool k_ = ready && ((pm##B & kept) == 0ull); \
            kept |= __ballot(k_); \
            decided |= __ballot(ready); \
            mydec = mydec || ready; \
        } \
    } \
    if (lane == 0) keptL[(C)] = kept; \
    const unsigned kb_ = (unsigned)(kept >> lane) & 1u; \
    unsigned nn_ = kb_ ? (n##B > 8u ? 8u : n##B) : 0u; \
    APPLY(0u, ea##B, 0)  APPLY(1u, ea##B, 16) APPLY(2u, ea##B, 32) APPLY(3u, ea##B, 48) \
    APPLY(4u, eb##B, 0)  APPLY(5u, eb##B, 16) APPLY(6u, eb##B, 32) APPLY(7u, eb##B, 48) \
    if (__any(kb_ && n##B > 8u)) { \
        unsigned nf_ = kb_ ? (n##B > CAP ? (unsigned)CAP : n##B) : 0u; \
        for (unsigned e_ = 8; e_ < nf_; ++e_) { \
            unsigned d_ = edgesOvf[(size_t)((C) * 64 + lane) * 56 + (e_ - 8)]; \
            atomicAnd(&alive[d_ >> 5], ~(1u << (d_ & 31))); \
        } \
    } \
    PF(B, (C) + 8); \
    asm volatile("s_waitcnt lgkmcnt(0)" ::: "memory"); \
} while (0)

__global__ __launch_bounds__(256, 2)
void mega_kernel(const float* __restrict__ rois,
                 const float* __restrict__ scores,
                 float* __restrict__ out,
                 unsigned* bar,
                 unsigned* cnt,
                 unsigned long long* prem,
                 unsigned* order,
                 float4* sboxes,
                 unsigned long long* edgesT,
                 unsigned short* edgesOvf) {
    __shared__ float sc[1024];
    __shared__ unsigned part[256];
    __shared__ float4 rb[64], cb[64];
    __shared__ unsigned alive[256];
    __shared__ unsigned long long keptL[128];

    const int t = threadIdx.x;
    const int b = blockIdx.x;
    const int gtid = b * 256 + t;

    // ---------------- P0a: zero cnt + premask ----------------
    {
        unsigned* z = cnt;              // cnt (8192 u32) then premask (16384 u32) contiguous
        if (gtid < 8192) z[gtid] = 0u;
        unsigned* pz = (unsigned*)prem;
        if (gtid < 16384) pz[gtid] = 0u;
    }

    // ---------------- P0b: rank + scatter (16 i per block, 16 threads per i) ----------------
    {
        const int ib  = b * 16;
        const int il  = t >> 4;
        const int i   = ib + il;
        const int sub = t & 15;
        const float si = scores[i];
        unsigned c = 0;
        for (int tile = 0; tile < 8; ++tile) {
            ((float4*)sc)[t] = ((const float4*)scores)[tile * 256 + t];
            __syncthreads();
            const int j0 = sub * 64;
            #pragma unroll 16
            for (int q = 0; q < 64; ++q) {
                int jj = j0 + q;
                float sj = sc[jj];
                int j = tile * 1024 + jj;
                c += (sj > si) || (sj == si && j < i);
            }
            __syncthreads();
        }
        part[t] = c;
        __syncthreads();
        if (t < 16) {
            const int i2 = ib + t;
            unsigned r = 0;
            #pragma unroll
            for (int q = 0; q < 16; ++q) r += part[t * 16 + q];
            order[r] = (unsigned)i2;
            sboxes[r] = ((const float4*)rois)[i2];
        }
    }

    // ---------------- barrier 1: all sboxes visible ----------------
    bar_arrive(bar);
    bar_wait(bar, NBLK);

    // ---------------- P1: edge build (persistent over 8256 upper-tri tile pairs) ----------------
    unsigned short* edgesTS = (unsigned short*)edgesT;
    for (int p = b; p < 8256; p += NBLK) {
        int ti = (int)((257.0f - sqrtf(66049.0f - 8.0f * (float)p)) * 0.5f);
        if (ti > 127) ti = 127;
        if (ti < 0) ti = 0;
        while (ti < 127 && (128 * (ti + 1) - ((ti + 1) * ti) / 2) <= p) ++ti;
        while (ti > 0 && (128 * ti - (ti * (ti - 1)) / 2) > p) --ti;
        const int tj = ti + (p - (128 * ti - (ti * (ti - 1)) / 2));

        if (t < 64) rb[t] = sboxes[ti * 64 + t];
        else if (t < 128) cb[t - 64] = sboxes[tj * 64 + (t - 64)];
        __syncthreads();
        #pragma unroll
        for (int kk = 0; kk < 16; ++kk) {
            int pp = kk * 256 + t;
            int r = pp >> 6, c = pp & 63;
            int is = ti * 64 + r, js = tj * 64 + c;
            if (js <= is) continue;
            if (iou_over(rb[r], cb[c])) {
                if (ti == tj) {
                    atomicOr(&prem[js], 1ull << r);
                } else {
                    unsigned pos = atomicAdd(&cnt[is], 1u);
                    if (pos < 8) {
                        edgesTS[(((is >> 6) * 2 + (pos >> 2)) * 64 + (is & 63)) * 4 + (pos & 3)] =
                            (unsigned short)js;
                    } else if (pos < CAP) {
                        edgesOvf[(size_t)is * 56 + (pos - 8)] = (unsigned short)js;
                    }
                }
            }
        }
        __syncthreads();
    }

    // ---------------- barrier 2: edges visible; 511 blocks exit ----------------
    bar_arrive(bar);
    if (b != 0) return;
    bar_wait(bar, 2 * NBLK);
    if (t >= 64) return;

    // ---------------- P2: serial resolve (wave 0 of block 0) ----------------
    const int lane = t;
    #pragma unroll
    for (int w = 0; w < 4; ++w) alive[w * 64 + lane] = 0xFFFFFFFFu;
    asm volatile("s_waitcnt lgkmcnt(0)" ::: "memory");

    unsigned long long pm0, pm1, pm2, pm3, pm4, pm5, pm6, pm7;
    unsigned n0, n1, n2, n3, n4, n5, n6, n7;
    unsigned long long ea0, ea1, ea2, ea3, ea4, ea5, ea6, ea7;
    unsigned long long eb0, eb1, eb2, eb3, eb4, eb5, eb6, eb7;

    PF(0, 0); PF(1, 1); PF(2, 2); PF(3, 3);
    PF(4, 4); PF(5, 5); PF(6, 6); PF(7, 7);

    for (int cc = 0; cc < 128; cc += 8) {
        STEP(0, cc + 0); STEP(1, cc + 1); STEP(2, cc + 2); STEP(3, cc + 3);
        STEP(4, cc + 4); STEP(5, cc + 5); STEP(6, cc + 6); STEP(7, cc + 7);
    }

    // ---------------- P3: output scatter (same wave) ----------------
    #pragma unroll 8
    for (int q = 0; q < 128; ++q) {
        int s = q * 64 + lane;
        unsigned long long kw = keptL[q];
        unsigned orig = order[s];
        float v = ((kw >> lane) & 1ull) ? scores[orig] : 0.0f;
        out[orig] = v;
    }
}

extern "C" void kernel_launch(void* const* d_in, const int* in_sizes, int n_in,
                              void* d_out, int out_size, void* d_ws, size_t ws_size,
                              hipStream_t stream) {
    const float* rois   = (const float*)d_in[0];
    const float* scores = (const float*)d_in[1];
    float* out = (float*)d_out;

    char* ws = (char*)d_ws;
    unsigned*            bar      = (unsigned*)(ws);
    unsigned*            cnt      = (unsigned*)(ws + 256);
    unsigned long long*  prem     = (unsigned long long*)(ws + 33024);
    unsigned*            order    = (unsigned*)(ws + 98560);
    float4*              sboxes   = (float4*)(ws + 131328);
    unsigned long long*  edgesT   = (unsigned long long*)(ws + 262400);
    unsigned short*      edgesOvf = (unsigned short*)(ws + 393472);

    hipMemsetAsync(ws, 0, 256, stream);   // barrier counter only; rest zeroed in-kernel

    mega_kernel<<<NBLK, 256, 0, stream>>>(rois, scores, out, bar, cnt, prem,
                                          order, sboxes, edgesT, edgesOvf);
}

// Round 6
// 160.002 us; speedup vs baseline: 1.9520x; 1.9520x over previous
//
#include <hip/hip_runtime.h>

#define N 8192
#define CAP 64
#define THR 0.2f

// ---- workspace layout (bytes) ----
// 0       rank     u32[8192]    32KB   \
// 32768   cnt      u32[8192]    32KB    > zeroed by one 320KB memset node
// 65536   prem     u64[8192*4] 256KB   /
// 327680  order    u32[8192]    32KB
// 360448  sboxes   f4 [8192]   128KB
// 491520  edgesT   u64[16384]  128KB
// 622592  edgesOvf u16[8192*56] 896KB

// ---------------- rank ----------------
__global__ __launch_bounds__(256) void rank_kernel(const float* __restrict__ scores,
                                                   unsigned* __restrict__ rank) {
    __shared__ float s[1024];
    const int jbase = blockIdx.y * 1024;
    for (int t = threadIdx.x; t < 1024; t += 256) s[t] = scores[jbase + t];
    __syncthreads();
    const int i = blockIdx.x * 256 + threadIdx.x;
    const float si = scores[i];
    unsigned c = 0;
    #pragma unroll 8
    for (int jj = 0; jj < 1024; ++jj) {
        float sj = s[jj];
        int j = jbase + jj;
        c += (sj > si) || (sj == si && j < i);
    }
    atomicAdd(&rank[i], c);
}

// ---------------- scatter into sorted order ----------------
__global__ __launch_bounds__(256) void scatter_kernel(const float* __restrict__ rois,
                                                      const unsigned* __restrict__ rank,
                                                      unsigned* __restrict__ order,
                                                      float4* __restrict__ sboxes) {
    const int i = blockIdx.x * 256 + threadIdx.x;
    const unsigned r = rank[i];
    order[r] = (unsigned)i;
    sboxes[r] = ((const float4*)rois)[i];
}

// ---------------- IoU (contraction-safe, matches numpy op order) ----------------
__device__ __forceinline__ bool iou_over(const float4 A, const float4 B) {
    float areaA = __fmul_rn(__fsub_rn(A.z, A.x), __fsub_rn(A.w, A.y));
    float areaB = __fmul_rn(__fsub_rn(B.z, B.x), __fsub_rn(B.w, B.y));
    float ix1 = fmaxf(A.x, B.x);
    float iy1 = fmaxf(A.y, B.y);
    float ix2 = fminf(A.z, B.z);
    float iy2 = fminf(A.w, B.w);
    float iw = fmaxf(__fsub_rn(ix2, ix1), 0.0f);
    float ih = fmaxf(__fsub_rn(iy2, iy1), 0.0f);
    float inter = __fmul_rn(iw, ih);
    float uni = __fsub_rn(__fadd_rn(areaA, areaB), inter);
    float iou = __fdiv_rn(inter, fmaxf(uni, 1e-9f));
    return iou > THR;
}

// ---------------- edge build: premask for same-256-chunk, fast8/overflow for cross ----------------
__global__ __launch_bounds__(256) void edge_kernel(const float4* __restrict__ sboxes,
                                                   unsigned long long* __restrict__ prem,
                                                   unsigned* __restrict__ cnt,
                                                   unsigned short* __restrict__ edgesTS,
                                                   unsigned short* __restrict__ edgesOvf) {
    const int k = blockIdx.x;
    int ti = (int)((257.0f - sqrtf(66049.0f - 8.0f * (float)k)) * 0.5f);
    if (ti > 127) ti = 127;
    if (ti < 0) ti = 0;
    while (ti < 127 && (128 * (ti + 1) - ((ti + 1) * ti) / 2) <= k) ++ti;
    while (ti > 0 && (128 * ti - (ti * (ti - 1)) / 2) > k) --ti;
    const int tj = ti + (k - (128 * ti - (ti * (ti - 1)) / 2));

    __shared__ float4 rb[64], cb[64];
    const int t = threadIdx.x;
    if (t < 64) rb[t] = sboxes[ti * 64 + t];
    else if (t < 128) cb[t - 64] = sboxes[tj * 64 + (t - 64)];
    __syncthreads();
    const bool same256 = (ti >> 2) == (tj >> 2);
    #pragma unroll
    for (int kk = 0; kk < 16; ++kk) {
        int pp = kk * 256 + t;
        int r = pp >> 6, c = pp & 63;
        int is = ti * 64 + r, js = tj * 64 + c;
        if (js <= is) continue;
        if (iou_over(rb[r], cb[c])) {
            if (same256) {
                atomicOr(&prem[(size_t)js * 4 + ((is >> 6) & 3)], 1ull << (is & 63));
            } else {
                unsigned pos = atomicAdd(&cnt[is], 1u);
                if (pos < 8) {
                    edgesTS[(((is >> 6) * 2 + (pos >> 2)) * 64 + (is & 63)) * 4 + (pos & 3)] =
                        (unsigned short)js;
                } else if (pos < CAP) {
                    edgesOvf[(size_t)is * 56 + (pos - 8)] = (unsigned short)js;
                }
            }
        }
    }
}

// ---------------- resolve + out: 1 wave, 32 chunks of 256 boxes ----------------
__device__ __forceinline__ unsigned long long resolve_group(bool av, unsigned long long pmw) {
    unsigned long long anz = __ballot(av && pmw != 0ull);
    unsigned long long kept = __ballot(av);
    if (anz != 0ull) {
        bool mydec = !av || (pmw == 0ull);
        unsigned long long decided = __ballot(mydec);
        kept = __ballot(av && (pmw == 0ull));
        while (decided != ~0ull) {
            bool ready = !mydec && ((pmw & ~decided) == 0ull);
            bool kk = ready && ((pmw & kept) == 0ull);
            kept |= __ballot(kk);
            decided |= __ballot(ready);
            mydec = mydec || ready;
        }
    }
    return kept;
}

#define PF(X, CH) do { \
    int ch_ = (CH); \
    if (ch_ < 32) { \
        int b0_ = ch_ * 256 + lane; \
        const ulonglong2* p2_ = (const ulonglong2*)prem; \
        pm0##X  = prem[(size_t)b0_ * 4]; \
        pm1##X  = p2_[(size_t)(b0_ + 64) * 2]; \
        pm2a##X = p2_[(size_t)(b0_ + 128) * 2]; \
        pm2b##X = prem[(size_t)(b0_ + 128) * 4 + 2]; \
        pm3a##X = p2_[(size_t)(b0_ + 192) * 2]; \
        pm3b##X = p2_[(size_t)(b0_ + 192) * 2 + 1]; \
        n0##X = cnt[b0_]; n1##X = cnt[b0_ + 64]; n2##X = cnt[b0_ + 128]; n3##X = cnt[b0_ + 192]; \
        int g4_ = ch_ * 4; \
        ea0##X = edgesT[((g4_ + 0) * 2 + 0) * 64 + lane]; eb0##X = edgesT[((g4_ + 0) * 2 + 1) * 64 + lane]; \
        ea1##X = edgesT[((g4_ + 1) * 2 + 0) * 64 + lane]; eb1##X = edgesT[((g4_ + 1) * 2 + 1) * 64 + lane]; \
        ea2##X = edgesT[((g4_ + 2) * 2 + 0) * 64 + lane]; eb2##X = edgesT[((g4_ + 2) * 2 + 1) * 64 + lane]; \
        ea3##X = edgesT[((g4_ + 3) * 2 + 0) * 64 + lane]; eb3##X = edgesT[((g4_ + 3) * 2 + 1) * 64 + lane]; \
    } \
} while (0)

#define APPLY(i, W, SH) { \
    unsigned d_ = (unsigned)((W) >> (SH)) & 0xFFFFu; \
    bool v_ = (i) < nn_; \
    unsigned a_ = v_ ? (d_ >> 5) : (unsigned)lane; \
    unsigned m_ = v_ ? ~(1u << (d_ & 31)) : ~0u; \
    atomicAnd(&alive[a_], m_); }

#define OVFG(KB, NV, BB) { \
    unsigned nf_ = (KB) ? ((NV) > (unsigned)CAP ? (unsigned)CAP : (NV)) : 0u; \
    for (unsigned e_ = 8; e_ < nf_; ++e_) { \
        unsigned d_ = edgesOvf[(size_t)(BB) * 56 + (e_ - 8)]; \
        atomicAnd(&alive[d_ >> 5], ~(1u << (d_ & 31))); } }

#define STEP(X, C) do { \
    unsigned aw0_ = alive[(C) * 8 + 0 + (lane >> 5)]; \
    unsigned aw1_ = alive[(C) * 8 + 2 + (lane >> 5)]; \
    unsigned aw2_ = alive[(C) * 8 + 4 + (lane >> 5)]; \
    unsigned aw3_ = alive[(C) * 8 + 6 + (lane >> 5)]; \
    const unsigned sh_ = lane & 31; \
    bool av0_ = (aw0_ >> sh_) & 1u; \
    unsigned long long k0_ = resolve_group(av0_, pm0##X); \
    bool av1_ = ((aw1_ >> sh_) & 1u) && ((pm1##X.x & k0_) == 0ull); \
    unsigned long long k1_ = resolve_group(av1_, pm1##X.y); \
    bool av2_ = ((aw2_ >> sh_) & 1u) && (((pm2a##X.x & k0_) | (pm2a##X.y & k1_)) == 0ull); \
    unsigned long long k2_ = resolve_group(av2_, pm2b##X); \
    bool av3_ = ((aw3_ >> sh_) & 1u) && (((pm3a##X.x & k0_) | (pm3a##X.y & k1_) | (pm3b##X.x & k2_)) == 0ull); \
    unsigned long long k3_ = resolve_group(av3_, pm3b##X.y); \
    if (lane == 0) { \
        keptL[(C) * 4 + 0] = k0_; keptL[(C) * 4 + 1] = k1_; \
        keptL[(C) * 4 + 2] = k2_; keptL[(C) * 4 + 3] = k3_; \
    } \
    unsigned kb0_ = (unsigned)(k0_ >> lane) & 1u; \
    unsigned kb1_ = (unsigned)(k1_ >> lane) & 1u; \
    unsigned kb2_ = (unsigned)(k2_ >> lane) & 1u; \
    unsigned kb3_ = (unsigned)(k3_ >> lane) & 1u; \
    unsigned nn_; \
    nn_ = kb0_ ? (n0##X > 8u ? 8u : n0##X) : 0u; \
    APPLY(0u, ea0##X, 0)  APPLY(1u, ea0##X, 16) APPLY(2u, ea0##X, 32) APPLY(3u, ea0##X, 48) \
    APPLY(4u, eb0##X, 0)  APPLY(5u, eb0##X, 16) APPLY(6u, eb0##X, 32) APPLY(7u, eb0##X, 48) \
    nn_ = kb1_ ? (n1##X > 8u ? 8u : n1##X) : 0u; \
    APPLY(0u, ea1##X, 0)  APPLY(1u, ea1##X, 16) APPLY(2u, ea1##X, 32) APPLY(3u, ea1##X, 48) \
    APPLY(4u, eb1##X, 0)  APPLY(5u, eb1##X, 16) APPLY(6u, eb1##X, 32) APPLY(7u, eb1##X, 48) \
    nn_ = kb2_ ? (n2##X > 8u ? 8u : n2##X) : 0u; \
    APPLY(0u, ea2##X, 0)  APPLY(1u, ea2##X, 16) APPLY(2u, ea2##X, 32) APPLY(3u, ea2##X, 48) \
    APPLY(4u, eb2##X, 0)  APPLY(5u, eb2##X, 16) APPLY(6u, eb2##X, 32) APPLY(7u, eb2##X, 48) \
    nn_ = kb3_ ? (n3##X > 8u ? 8u : n3##X) : 0u; \
    APPLY(0u, ea3##X, 0)  APPLY(1u, ea3##X, 16) APPLY(2u, ea3##X, 32) APPLY(3u, ea3##X, 48) \
    APPLY(4u, eb3##X, 0)  APPLY(5u, eb3##X, 16) APPLY(6u, eb3##X, 32) APPLY(7u, eb3##X, 48) \
    if (__any((kb0_ && n0##X > 8u) || (kb1_ && n1##X > 8u) || \
              (kb2_ && n2##X > 8u) || (kb3_ && n3##X > 8u))) { \
        OVFG(kb0_, n0##X, (C) * 256 + lane) \
        OVFG(kb1_, n1##X, (C) * 256 + 64 + lane) \
        OVFG(kb2_, n2##X, (C) * 256 + 128 + lane) \
        OVFG(kb3_, n3##X, (C) * 256 + 192 + lane) \
    } \
    PF(X, (C) + 2); \
    asm volatile("s_waitcnt lgkmcnt(0)" ::: "memory"); \
} while (0)

__global__ __launch_bounds__(64)
void resolve_out_kernel(const unsigned long long* __restrict__ prem,
                        const unsigned* __restrict__ cnt,
                        const unsigned long long* __restrict__ edgesT,
                        const unsigned short* __restrict__ edgesOvf,
                        const unsigned* __restrict__ order,
                        const float* __restrict__ scores,
                        float* __restrict__ out) {
    __shared__ unsigned alive[256];          // 8192-bit alive bitmap
    __shared__ unsigned long long keptL[128];
    const int lane = threadIdx.x;
    #pragma unroll
    for (int w = 0; w < 4; ++w) alive[w * 64 + lane] = 0xFFFFFFFFu;
    asm volatile("s_waitcnt lgkmcnt(0)" ::: "memory");

    unsigned long long pm0A, pm2bA, pm0B, pm2bB;
    ulonglong2 pm1A, pm2aA, pm3aA, pm3bA, pm1B, pm2aB, pm3aB, pm3bB;
    unsigned n0A, n1A, n2A, n3A, n0B, n1B, n2B, n3B;
    unsigned long long ea0A, eb0A, ea1A, eb1A, ea2A, eb2A, ea3A, eb3A;
    unsigned long long ea0B, eb0B, ea1B, eb1B, ea2B, eb2B, ea3B, eb3B;

    PF(A, 0); PF(B, 1);

    for (int cc = 0; cc < 32; cc += 2) {
        STEP(A, cc);
        STEP(B, cc + 1);
    }

    // fused output scatter
    #pragma unroll 4
    for (int q = 0; q < 128; ++q) {
        int s = q * 64 + lane;
        unsigned long long kw = keptL[q];
        unsigned orig = order[s];
        out[orig] = ((kw >> lane) & 1ull) ? scores[orig] : 0.0f;
    }
}

extern "C" void kernel_launch(void* const* d_in, const int* in_sizes, int n_in,
                              void* d_out, int out_size, void* d_ws, size_t ws_size,
                              hipStream_t stream) {
    const float* rois   = (const float*)d_in[0];
    const float* scores = (const float*)d_in[1];
    float* out = (float*)d_out;

    char* ws = (char*)d_ws;
    unsigned*            rank     = (unsigned*)(ws);
    unsigned*            cnt      = (unsigned*)(ws + 32768);
    unsigned long long*  prem     = (unsigned long long*)(ws + 65536);
    unsigned*            order    = (unsigned*)(ws + 327680);
    float4*              sboxes   = (float4*)(ws + 360448);
    unsigned long long*  edgesT   = (unsigned long long*)(ws + 491520);
    unsigned short*      edgesOvf = (unsigned short*)(ws + 622592);

    hipMemsetAsync(ws, 0, 327680, stream);   // rank + cnt + prem

    rank_kernel<<<dim3(32, 8), 256, 0, stream>>>(scores, rank);
    scatter_kernel<<<32, 256, 0, stream>>>(rois, rank, order, sboxes);
    edge_kernel<<<8256, 256, 0, stream>>>(sboxes, prem, cnt,
                                          (unsigned short*)edgesT, edgesOvf);
    resolve_out_kernel<<<1, 64, 0, stream>>>(prem, cnt, edgesT, edgesOvf,
                                             order, scores, out);
}

// Round 7
// 134.621 us; speedup vs baseline: 2.3200x; 1.1885x over previous
//
#include <hip/hip_runtime.h>

#define N 8192
#define CAP 64
#define THR 0.2f

// ---- workspace layout (bytes) ----
// 0        cnt      u32[8192]     32KB  \ zeroed in-kernel (96KB contiguous)
// 32768    premask  u64[8192]     64KB  /
// 98304    order    u32[8192]     32KB
// 131072   sboxes   f4 [8192]    128KB
// 262144   edgesT   u64[16384]   128KB
// 393216   edgesOvf u16[8192*56] 896KB
// 1310720  keptw    u64[128]       1KB

// ---------------- fused: zero ws + rank + scatter ----------------
// 256 blocks x 256 threads; 8 threads per box i scan all 8192 scores.
__global__ __launch_bounds__(256) void rank_scatter_kernel(const float* __restrict__ rois,
                                                           const float* __restrict__ scores,
                                                           uint4* __restrict__ zbase,
                                                           unsigned* __restrict__ order,
                                                           float4* __restrict__ sboxes) {
    __shared__ float sc[1024];
    const int t = threadIdx.x, b = blockIdx.x;

    // zero cnt+premask (96KB = 6144 uint4): first 6144 global threads
    const int g = b * 256 + t;
    if (g < 6144) zbase[g] = make_uint4(0, 0, 0, 0);

    const int il = t >> 3, sub = t & 7;
    const int i = b * 32 + il;
    const float si = scores[i];
    unsigned c = 0;
    for (int tile = 0; tile < 8; ++tile) {
        ((float4*)sc)[t] = ((const float4*)scores)[tile * 256 + t];
        __syncthreads();
        #pragma unroll 16
        for (int q = 0; q < 128; ++q) {
            int jj = q * 8 + sub;            // 8 distinct words, 8 banks, 8-way broadcast
            float sj = sc[jj];
            int j = tile * 1024 + jj;
            c += (sj > si) || (sj == si && j < i);
        }
        __syncthreads();
    }
    c += __shfl_xor(c, 1);
    c += __shfl_xor(c, 2);
    c += __shfl_xor(c, 4);
    if (sub == 0) {
        order[c] = (unsigned)i;
        sboxes[c] = ((const float4*)rois)[i];
    }
}

// ---------------- IoU (contraction-safe, matches numpy op order) ----------------
__device__ __forceinline__ bool iou_over(const float4 A, const float4 B) {
    float areaA = __fmul_rn(__fsub_rn(A.z, A.x), __fsub_rn(A.w, A.y));
    float areaB = __fmul_rn(__fsub_rn(B.z, B.x), __fsub_rn(B.w, B.y));
    float ix1 = fmaxf(A.x, B.x);
    float iy1 = fmaxf(A.y, B.y);
    float ix2 = fminf(A.z, B.z);
    float iy2 = fminf(A.w, B.w);
    float iw = fmaxf(__fsub_rn(ix2, ix1), 0.0f);
    float ih = fmaxf(__fsub_rn(iy2, iy1), 0.0f);
    float inter = __fmul_rn(iw, ih);
    float uni = __fsub_rn(__fadd_rn(areaA, areaB), inter);
    float iou = __fdiv_rn(inter, fmaxf(uni, 1e-9f));
    return iou > THR;
}

// ---------------- edge build (R4-proven): premask within 64-chunk, fast8/ovf across ----------------
__global__ __launch_bounds__(256) void edge_kernel(const float4* __restrict__ sboxes,
                                                   unsigned long long* __restrict__ premask,
                                                   unsigned* __restrict__ cnt,
                                                   unsigned short* __restrict__ edgesTS,
                                                   unsigned short* __restrict__ edgesOvf) {
    const int k = blockIdx.x;
    int ti = (int)((257.0f - sqrtf(66049.0f - 8.0f * (float)k)) * 0.5f);
    if (ti > 127) ti = 127;
    if (ti < 0) ti = 0;
    while (ti < 127 && (128 * (ti + 1) - ((ti + 1) * ti) / 2) <= k) ++ti;
    while (ti > 0 && (128 * ti - (ti * (ti - 1)) / 2) > k) --ti;
    const int tj = ti + (k - (128 * ti - (ti * (ti - 1)) / 2));

    __shared__ float4 rb[64], cb[64];
    const int t = threadIdx.x;
    if (t < 64) rb[t] = sboxes[ti * 64 + t];
    else if (t < 128) cb[t - 64] = sboxes[tj * 64 + (t - 64)];
    __syncthreads();
    #pragma unroll
    for (int kk = 0; kk < 16; ++kk) {
        int pp = kk * 256 + t;
        int r = pp >> 6, c = pp & 63;
        int is = ti * 64 + r, js = tj * 64 + c;
        if (js <= is) continue;
        if (iou_over(rb[r], cb[c])) {
            if (ti == tj) {
                atomicOr(&premask[js], 1ull << r);
            } else {
                unsigned pos = atomicAdd(&cnt[is], 1u);
                if (pos < 8) {
                    edgesTS[(((is >> 6) * 2 + (pos >> 2)) * 64 + (is & 63)) * 4 + (pos & 3)] =
                        (unsigned short)js;
                } else if (pos < CAP) {
                    edgesOvf[(size_t)is * 56 + (pos - 8)] = (unsigned short)js;
                }
            }
        }
    }
}

// ---------------- sequential greedy resolve (R4-proven logic, 1-wave VGPR budget) ----------------
#define PF(B, CH) do { \
    int ch_ = (CH); \
    if (ch_ < 128) { \
        int pb_ = ch_ * 64 + lane; \
        pm##B = premask[pb_]; \
        n##B  = cnt[pb_]; \
        ea##B = edgesT[(ch_ * 2 + 0) * 64 + lane]; \
        eb##B = edgesT[(ch_ * 2 + 1) * 64 + lane]; \
    } \
} while (0)

#define APPLY(i, W, SH) { \
    unsigned d_ = (unsigned)((W) >> (SH)) & 0xFFFFu; \
    bool v_ = (i) < nn_; \
    unsigned a_ = v_ ? (d_ >> 5) : (unsigned)lane; \
    unsigned m_ = v_ ? ~(1u << (d_ & 31)) : ~0u; \
    atomicAnd(&alive[a_], m_); }

#define STEP(B, C) do { \
    const unsigned av_ = (alive[(C) * 2 + (lane >> 5)] >> (lane & 31)) & 1u; \
    unsigned long long anz = __ballot(pm##B != 0ull); \
    unsigned long long kept = __ballot(av_ != 0u); \
    if (anz != 0ull) { \
        bool mydec = !av_ || (pm##B == 0ull); \
        unsigned long long decided = __ballot(mydec); \
        kept = __ballot(av_ && (pm##B == 0ull)); \
        while (decided != ~0ull) { \
            bool ready = !mydec && ((pm##B & ~decided) == 0ull); \
            bool k_ = ready && ((pm##B & kept) == 0ull); \
            kept |= __ballot(k_); \
            decided |= __ballot(ready); \
            mydec = mydec || ready; \
        } \
    } \
    if (lane == 0) keptw[(C)] = kept; \
    const unsigned kb_ = (unsigned)(kept >> lane) & 1u; \
    unsigned nn_ = kb_ ? (n##B > 8u ? 8u : n##B) : 0u; \
    APPLY(0u, ea##B, 0)  APPLY(1u, ea##B, 16) APPLY(2u, ea##B, 32) APPLY(3u, ea##B, 48) \
    APPLY(4u, eb##B, 0)  APPLY(5u, eb##B, 16) APPLY(6u, eb##B, 32) APPLY(7u, eb##B, 48) \
    if (__any(kb_ && n##B > 8u)) { \
        unsigned nf_ = kb_ ? (n##B > CAP ? (unsigned)CAP : n##B) : 0u; \
        for (unsigned e_ = 8; e_ < nf_; ++e_) { \
            unsigned d_ = edgesOvf[(size_t)((C) * 64 + lane) * 56 + (e_ - 8)]; \
            atomicAnd(&alive[d_ >> 5], ~(1u << (d_ & 31))); \
        } \
    } \
    PF(B, (C) + 8); \
    asm volatile("s_waitcnt lgkmcnt(0)" ::: "memory"); \
} while (0)

__global__ __launch_bounds__(64, 1)
void resolve_kernel(const unsigned long long* __restrict__ premask,
                    const unsigned* __restrict__ cnt,
                    const unsigned long long* __restrict__ edgesT,
                    const unsigned short* __restrict__ edgesOvf,
                    unsigned long long* __restrict__ keptw) {
    __shared__ unsigned alive[256];       // 8192-bit alive bitmap
    const int lane = threadIdx.x;
    #pragma unroll
    for (int w = 0; w < 4; ++w) alive[w * 64 + lane] = 0xFFFFFFFFu;
    asm volatile("s_waitcnt lgkmcnt(0)" ::: "memory");

    unsigned long long pm0, pm1, pm2, pm3, pm4, pm5, pm6, pm7;
    unsigned n0, n1, n2, n3, n4, n5, n6, n7;
    unsigned long long ea0, ea1, ea2, ea3, ea4, ea5, ea6, ea7;
    unsigned long long eb0, eb1, eb2, eb3, eb4, eb5, eb6, eb7;

    PF(0, 0); PF(1, 1); PF(2, 2); PF(3, 3);
    PF(4, 4); PF(5, 5); PF(6, 6); PF(7, 7);

    for (int cc = 0; cc < 128; cc += 8) {
        STEP(0, cc + 0); STEP(1, cc + 1); STEP(2, cc + 2); STEP(3, cc + 3);
        STEP(4, cc + 4); STEP(5, cc + 5); STEP(6, cc + 6); STEP(7, cc + 7);
    }
}

// ---------------- output scatter (parallel) ----------------
__global__ __launch_bounds__(256) void out_kernel(const float* __restrict__ scores,
                                                  const unsigned* __restrict__ order,
                                                  const unsigned long long* __restrict__ keptw,
                                                  float* __restrict__ out) {
    const int s = blockIdx.x * 256 + threadIdx.x;
    const unsigned orig = order[s];
    const unsigned keep = (unsigned)((keptw[s >> 6] >> (s & 63)) & 1ull);
    out[orig] = keep ? scores[orig] : 0.0f;
}

extern "C" void kernel_launch(void* const* d_in, const int* in_sizes, int n_in,
                              void* d_out, int out_size, void* d_ws, size_t ws_size,
                              hipStream_t stream) {
    const float* rois   = (const float*)d_in[0];
    const float* scores = (const float*)d_in[1];
    float* out = (float*)d_out;

    char* ws = (char*)d_ws;
    unsigned*            cnt      = (unsigned*)(ws);
    unsigned long long*  premask  = (unsigned long long*)(ws + 32768);
    unsigned*            order    = (unsigned*)(ws + 98304);
    float4*              sboxes   = (float4*)(ws + 131072);
    unsigned long long*  edgesT   = (unsigned long long*)(ws + 262144);
    unsigned short*      edgesOvf = (unsigned short*)(ws + 393216);
    unsigned long long*  keptw    = (unsigned long long*)(ws + 1310720);

    rank_scatter_kernel<<<256, 256, 0, stream>>>(rois, scores, (uint4*)ws, order, sboxes);
    edge_kernel<<<8256, 256, 0, stream>>>(sboxes, premask, cnt,
                                          (unsigned short*)edgesT, edgesOvf);
    resolve_kernel<<<1, 64, 0, stream>>>(premask, cnt, edgesT, edgesOvf, keptw);
    out_kernel<<<32, 256, 0, stream>>>(scores, order, keptw, out);
}